// Round 2
// baseline (1050.824 us; speedup 1.0000x reference)
//
#include <hip/hip_runtime.h>

#define BB   32
#define EE   256
#define HH   64
#define WW   64
#define HIDN 256
#define KC   8

__device__ __forceinline__ float bflo(unsigned u) { return __uint_as_float(u << 16); }
__device__ __forceinline__ float bfhi(unsigned u) { return __uint_as_float(u & 0xffff0000u); }
__device__ __forceinline__ unsigned f2bf(float f) {
  unsigned u = __float_as_uint(f);
  u += 0x7fffu + ((u >> 16) & 1u);   // round-to-nearest-even
  return u >> 16;
}

// FMA a scalar into a float4 accumulator, componentwise (pure SSA, SROA-safe).
#define FMA4(A, S, V)                \
  A.x = fmaf((S), (V).x, A.x);       \
  A.y = fmaf((S), (V).y, A.y);       \
  A.z = fmaf((S), (V).z, A.z);       \
  A.w = fmaf((S), (V).w, A.w);

// One workgroup = one (b,h) slice. 256 threads.
__global__ __launch_bounds__(256, 3) void sep_attn_fused(
    const float* __restrict__ x, const float* __restrict__ Wqkv,
    const float* __restrict__ bqkv, const float* __restrict__ Wout,
    const float* __restrict__ bout, float* __restrict__ out)
{
  __shared__ __align__(16) float    qpart[4 * 64];
  __shared__ __align__(16) float    ss[64];
  __shared__ __align__(16) float    xbar_s[EE];
  __shared__ __align__(16) float    cvs[EE];
  __shared__ __align__(16) float    wchunk[KC * 256];   // [kk][c]
  __shared__ __align__(16) float    xchunk[KC * 64];    // [kk][w]
  __shared__ __align__(16) unsigned gsu[EE * WW / 2];   // gated, bf16x2 packed, [c][w]

  const int tid = threadIdx.x;
  const int bh  = blockIdx.x;
  const int b   = bh >> 6;
  const int h   = bh & 63;
  const int gbase = (b * EE) * 4096 + h * 64;   // x[b,c,h,w] = x[gbase + c*4096 + w]

  // ---- Phase 1: query partials (coalesced over w) ----
  {
    const int w  = tid & 63;
    const int cg = tid >> 6;            // wave-uniform -> Wqkv loads are scalar
    float q = 0.f;
    const float* xp = x + gbase + (cg * 64) * 4096 + w;
    #pragma unroll 8
    for (int cc = 0; cc < 64; ++cc)
      q = fmaf(Wqkv[cg * 64 + cc], xp[cc * 4096], q);
    qpart[cg * 64 + w] = q;
  }
  __syncthreads();

  // ---- Phase 2: softmax over the 64 w positions (one wave) ----
  if (tid < 64) {
    float q = qpart[tid] + qpart[64 + tid] + qpart[128 + tid] + qpart[192 + tid] + bqkv[0];
    float m = q;
    #pragma unroll
    for (int off = 32; off; off >>= 1) m = fmaxf(m, __shfl_xor(m, off));
    float e = expf(q - m);
    float s = e;
    #pragma unroll
    for (int off = 32; off; off >>= 1) s += __shfl_xor(s, off);
    ss[tid] = e / s;
  }
  __syncthreads();

  // ---- Phase 3: xbar[c] = sum_w score[w] * x[b,c,h,w]  (L2-hot re-read) ----
  {
    const int c = tid;
    float acc = 0.f;
    #pragma unroll
    for (int f = 0; f < 16; ++f) {
      float4 sv = *(const float4*)&ss[f * 4];                       // LDS broadcast
      float4 xv = *(const float4*)&x[gbase + c * 4096 + f * 4];
      acc += sv.x * xv.x + sv.y * xv.y + sv.z * xv.z + sv.w * xv.w;
    }
    xbar_s[c] = acc;
  }
  __syncthreads();

  // ---- Phase 4: cv[c] = Wk_row(c) . xbar + bk[c]  (key GEMM collapsed) ----
  {
    const int c = tid;
    const float* wk = Wqkv + (1 + c) * EE;
    float acc = 0.f;
    #pragma unroll 8
    for (int f = 0; f < 64; ++f) {
      float4 wv = *(const float4*)&wk[f * 4];
      float4 xb = *(const float4*)&xbar_s[f * 4];                   // LDS broadcast
      acc += wv.x * xb.x + wv.y * xb.y + wv.z * xb.z + wv.w * xb.w;
    }
    cvs[c] = acc + bqkv[1 + c];
  }
  // cvs visibility guaranteed by the syncthreads inside the GEMM loop below

  const int i = tid >> 3;   // channel group: c = i*8 .. i*8+7
  const int j = tid & 7;    // w group:       w = j*8 .. j*8+7

  // ---- Phase 5: value GEMM (256x64 tile, k over 256 input channels) ----
  const float4 z4 = make_float4(0.f, 0.f, 0.f, 0.f);
  float4 vA0 = z4, vA1 = z4, vA2 = z4, vA3 = z4, vA4 = z4, vA5 = z4, vA6 = z4, vA7 = z4;
  float4 vB0 = z4, vB1 = z4, vB2 = z4, vB3 = z4, vB4 = z4, vB5 = z4, vB6 = z4, vB7 = z4;

  for (int k0 = 0; k0 < EE; k0 += KC) {
    __syncthreads();
    {
      const float* wrow = Wqkv + (257 + tid) * EE + k0;   // value weight rows
      float4 a0 = *(const float4*)&wrow[0];
      float4 a1 = *(const float4*)&wrow[4];
      wchunk[0*256 + tid] = a0.x; wchunk[1*256 + tid] = a0.y;
      wchunk[2*256 + tid] = a0.z; wchunk[3*256 + tid] = a0.w;
      wchunk[4*256 + tid] = a1.x; wchunk[5*256 + tid] = a1.y;
      wchunk[6*256 + tid] = a1.z; wchunk[7*256 + tid] = a1.w;
    }
    if (tid < 128) {
      const int c = tid >> 4, f4 = tid & 15;
      *(float4*)&xchunk[c * 64 + f4 * 4] =
          *(const float4*)&x[gbase + (k0 + c) * 4096 + f4 * 4];
    }
    __syncthreads();
    #pragma unroll
    for (int kk = 0; kk < KC; ++kk) {
      const float4 w0 = *(const float4*)&wchunk[kk*256 + i*8];
      const float4 w1 = *(const float4*)&wchunk[kk*256 + i*8 + 4];
      const float4 x0 = *(const float4*)&xchunk[kk*64 + j*8];
      const float4 x1 = *(const float4*)&xchunk[kk*64 + j*8 + 4];
      FMA4(vA0, w0.x, x0) FMA4(vB0, w0.x, x1)
      FMA4(vA1, w0.y, x0) FMA4(vB1, w0.y, x1)
      FMA4(vA2, w0.z, x0) FMA4(vB2, w0.z, x1)
      FMA4(vA3, w0.w, x0) FMA4(vB3, w0.w, x1)
      FMA4(vA4, w1.x, x0) FMA4(vB4, w1.x, x1)
      FMA4(vA5, w1.y, x0) FMA4(vB5, w1.y, x1)
      FMA4(vA6, w1.z, x0) FMA4(vB6, w1.z, x1)
      FMA4(vA7, w1.w, x0) FMA4(vB7, w1.w, x1)
    }
  }

  // ---- Phase 6: relu + gate, pack bf16 into LDS (pure component code) ----
  {
    const float4 cv0 = *(const float4*)&cvs[i*8];
    const float4 cv1 = *(const float4*)&cvs[i*8 + 4];
    #define GATE_ROW(N, CVC)                                            \
    {                                                                   \
      const float bias = bqkv[257 + i*8 + N];                           \
      float4 gA, gB;                                                    \
      gA.x = fmaxf(vA##N.x + bias, 0.f) * (CVC);                        \
      gA.y = fmaxf(vA##N.y + bias, 0.f) * (CVC);                        \
      gA.z = fmaxf(vA##N.z + bias, 0.f) * (CVC);                        \
      gA.w = fmaxf(vA##N.w + bias, 0.f) * (CVC);                        \
      gB.x = fmaxf(vB##N.x + bias, 0.f) * (CVC);                        \
      gB.y = fmaxf(vB##N.y + bias, 0.f) * (CVC);                        \
      gB.z = fmaxf(vB##N.z + bias, 0.f) * (CVC);                        \
      gB.w = fmaxf(vB##N.w + bias, 0.f) * (CVC);                        \
      uint4 U;                                                          \
      U.x = f2bf(gA.x) | (f2bf(gA.y) << 16);                            \
      U.y = f2bf(gA.z) | (f2bf(gA.w) << 16);                            \
      U.z = f2bf(gB.x) | (f2bf(gB.y) << 16);                            \
      U.w = f2bf(gB.z) | (f2bf(gB.w) << 16);                            \
      *(uint4*)&gsu[(i*8 + N) * 32 + j * 4] = U;                        \
    }
    GATE_ROW(0, cv0.x) GATE_ROW(1, cv0.y) GATE_ROW(2, cv0.z) GATE_ROW(3, cv0.w)
    GATE_ROW(4, cv1.x) GATE_ROW(5, cv1.y) GATE_ROW(6, cv1.z) GATE_ROW(7, cv1.w)
    #undef GATE_ROW
  }

  // ---- Phase 7: output GEMM (k over 256 gated channels) ----
  float4 oA0 = z4, oA1 = z4, oA2 = z4, oA3 = z4, oA4 = z4, oA5 = z4, oA6 = z4, oA7 = z4;
  float4 oB0 = z4, oB1 = z4, oB2 = z4, oB3 = z4, oB4 = z4, oB5 = z4, oB6 = z4, oB7 = z4;

  for (int k0 = 0; k0 < HIDN; k0 += KC) {
    __syncthreads();   // publishes gsu on first iter, protects wchunk reuse
    {
      const float* wrow = Wout + tid * HIDN + k0;
      float4 a0 = *(const float4*)&wrow[0];
      float4 a1 = *(const float4*)&wrow[4];
      wchunk[0*256 + tid] = a0.x; wchunk[1*256 + tid] = a0.y;
      wchunk[2*256 + tid] = a0.z; wchunk[3*256 + tid] = a0.w;
      wchunk[4*256 + tid] = a1.x; wchunk[5*256 + tid] = a1.y;
      wchunk[6*256 + tid] = a1.z; wchunk[7*256 + tid] = a1.w;
    }
    __syncthreads();
    #pragma unroll
    for (int kk = 0; kk < KC; ++kk) {
      const float4 w0 = *(const float4*)&wchunk[kk*256 + i*8];
      const float4 w1 = *(const float4*)&wchunk[kk*256 + i*8 + 4];
      const uint4  gu = *(const uint4*)&gsu[(k0 + kk) * 32 + j * 4];
      float4 g0, g1;
      g0.x = bflo(gu.x); g0.y = bfhi(gu.x); g0.z = bflo(gu.y); g0.w = bfhi(gu.y);
      g1.x = bflo(gu.z); g1.y = bfhi(gu.z); g1.z = bflo(gu.w); g1.w = bfhi(gu.w);
      FMA4(oA0, w0.x, g0) FMA4(oB0, w0.x, g1)
      FMA4(oA1, w0.y, g0) FMA4(oB1, w0.y, g1)
      FMA4(oA2, w0.z, g0) FMA4(oB2, w0.z, g1)
      FMA4(oA3, w0.w, g0) FMA4(oB3, w0.w, g1)
      FMA4(oA4, w1.x, g0) FMA4(oB4, w1.x, g1)
      FMA4(oA5, w1.y, g0) FMA4(oB5, w1.y, g1)
      FMA4(oA6, w1.z, g0) FMA4(oB6, w1.z, g1)
      FMA4(oA7, w1.w, g0) FMA4(oB7, w1.w, g1)
    }
  }

  // ---- Phase 8: bias + coalesced store (pure component code) ----
  {
    #define STORE_ROW(N)                                                \
    {                                                                   \
      const int o = i*8 + N;                                            \
      const float bo = bout[o];                                         \
      float* op = out + (b * EE + o) * 4096 + h * 64 + j * 8;           \
      float4 s0, s1;                                                    \
      s0.x = oA##N.x + bo; s0.y = oA##N.y + bo;                         \
      s0.z = oA##N.z + bo; s0.w = oA##N.w + bo;                         \
      s1.x = oB##N.x + bo; s1.y = oB##N.y + bo;                         \
      s1.z = oB##N.z + bo; s1.w = oB##N.w + bo;                         \
      *(float4*)&op[0] = s0;                                            \
      *(float4*)&op[4] = s1;                                            \
    }
    STORE_ROW(0) STORE_ROW(1) STORE_ROW(2) STORE_ROW(3)
    STORE_ROW(4) STORE_ROW(5) STORE_ROW(6) STORE_ROW(7)
    #undef STORE_ROW
  }
}

extern "C" void kernel_launch(void* const* d_in, const int* in_sizes, int n_in,
                              void* d_out, int out_size, void* d_ws, size_t ws_size,
                              hipStream_t stream) {
  const float* x    = (const float*)d_in[0];
  const float* Wqkv = (const float*)d_in[1];
  const float* bqkv = (const float*)d_in[2];
  const float* Wout = (const float*)d_in[3];
  const float* bout = (const float*)d_in[4];
  float* out = (float*)d_out;
  dim3 grid(BB * HH);   // 2048 workgroups, one per (b,h)
  dim3 block(256);
  hipLaunchKernelGGL(sep_attn_fused, grid, block, 0, stream,
                     x, Wqkv, bqkv, Wout, bout, out);
}

// Round 3
// 697.760 us; speedup vs baseline: 1.5060x; 1.5060x over previous
//
#include <hip/hip_runtime.h>

#define BB   32
#define EE   256
#define HH   64
#define WW   64
#define HIDN 256
#define KC   8

__device__ __forceinline__ float bflo(unsigned u) { return __uint_as_float(u << 16); }
__device__ __forceinline__ float bfhi(unsigned u) { return __uint_as_float(u & 0xffff0000u); }
__device__ __forceinline__ unsigned f2bf(float f) {
  unsigned u = __float_as_uint(f);
  u += 0x7fffu + ((u >> 16) & 1u);   // round-to-nearest-even
  return u >> 16;
}

// FMA a scalar into a float4 accumulator, componentwise (pure SSA, SROA-safe).
#define FMA4(A, S, V)                \
  A.x = fmaf((S), (V).x, A.x);       \
  A.y = fmaf((S), (V).y, A.y);       \
  A.z = fmaf((S), (V).z, A.z);       \
  A.w = fmaf((S), (V).w, A.w);

// One workgroup = one (b,h) slice. 256 threads.
// __launch_bounds__(256, 1): waves-per-eu=1 -> VGPR cap 512. The (256,3)
// variant capped allocation at 84 VGPR and spilled the 128-VGPR accumulator
// tile to scratch (WRITE_SIZE 1.86 GB vs 0.13 GB ideal). Occupancy will be
// VGPR-limited (~2 blocks/CU) which is fine — spill removal dominates.
__global__ __launch_bounds__(256, 1) void sep_attn_fused(
    const float* __restrict__ x, const float* __restrict__ Wqkv,
    const float* __restrict__ bqkv, const float* __restrict__ Wout,
    const float* __restrict__ bout, float* __restrict__ out)
{
  __shared__ __align__(16) float    qpart[4 * 64];
  __shared__ __align__(16) float    ss[64];
  __shared__ __align__(16) float    xbar_s[EE];
  __shared__ __align__(16) float    cvs[EE];
  __shared__ __align__(16) float    wchunk[KC * 256];   // [kk][c]
  __shared__ __align__(16) float    xchunk[KC * 64];    // [kk][w]
  __shared__ __align__(16) unsigned gsu[EE * WW / 2];   // gated, bf16x2 packed, [c][w]

  const int tid = threadIdx.x;
  const int bh  = blockIdx.x;
  const int b   = bh >> 6;
  const int h   = bh & 63;
  const int gbase = (b * EE) * 4096 + h * 64;   // x[b,c,h,w] = x[gbase + c*4096 + w]

  // ---- Phase 1: query partials (coalesced over w) ----
  {
    const int w  = tid & 63;
    const int cg = tid >> 6;            // wave-uniform -> Wqkv loads are scalar
    float q = 0.f;
    const float* xp = x + gbase + (cg * 64) * 4096 + w;
    #pragma unroll 8
    for (int cc = 0; cc < 64; ++cc)
      q = fmaf(Wqkv[cg * 64 + cc], xp[cc * 4096], q);
    qpart[cg * 64 + w] = q;
  }
  __syncthreads();

  // ---- Phase 2: softmax over the 64 w positions (one wave) ----
  if (tid < 64) {
    float q = qpart[tid] + qpart[64 + tid] + qpart[128 + tid] + qpart[192 + tid] + bqkv[0];
    float m = q;
    #pragma unroll
    for (int off = 32; off; off >>= 1) m = fmaxf(m, __shfl_xor(m, off));
    float e = expf(q - m);
    float s = e;
    #pragma unroll
    for (int off = 32; off; off >>= 1) s += __shfl_xor(s, off);
    ss[tid] = e / s;
  }
  __syncthreads();

  // ---- Phase 3: xbar[c] = sum_w score[w] * x[b,c,h,w]  (L2-hot re-read) ----
  {
    const int c = tid;
    float acc = 0.f;
    #pragma unroll
    for (int f = 0; f < 16; ++f) {
      float4 sv = *(const float4*)&ss[f * 4];                       // LDS broadcast
      float4 xv = *(const float4*)&x[gbase + c * 4096 + f * 4];
      acc += sv.x * xv.x + sv.y * xv.y + sv.z * xv.z + sv.w * xv.w;
    }
    xbar_s[c] = acc;
  }
  __syncthreads();

  // ---- Phase 4: cv[c] = Wk_row(c) . xbar + bk[c]  (key GEMM collapsed) ----
  {
    const int c = tid;
    const float* wk = Wqkv + (1 + c) * EE;
    float acc = 0.f;
    #pragma unroll 8
    for (int f = 0; f < 64; ++f) {
      float4 wv = *(const float4*)&wk[f * 4];
      float4 xb = *(const float4*)&xbar_s[f * 4];                   // LDS broadcast
      acc += wv.x * xb.x + wv.y * xb.y + wv.z * xb.z + wv.w * xb.w;
    }
    cvs[c] = acc + bqkv[1 + c];
  }
  // cvs visibility guaranteed by the syncthreads inside the GEMM loop below

  const int i = tid >> 3;   // channel group: c = i*8 .. i*8+7
  const int j = tid & 7;    // w group:       w = j*8 .. j*8+7

  // ---- Phase 5: value GEMM (256x64 tile, k over 256 input channels) ----
  const float4 z4 = make_float4(0.f, 0.f, 0.f, 0.f);
  float4 vA0 = z4, vA1 = z4, vA2 = z4, vA3 = z4, vA4 = z4, vA5 = z4, vA6 = z4, vA7 = z4;
  float4 vB0 = z4, vB1 = z4, vB2 = z4, vB3 = z4, vB4 = z4, vB5 = z4, vB6 = z4, vB7 = z4;

  for (int k0 = 0; k0 < EE; k0 += KC) {
    __syncthreads();
    {
      const float* wrow = Wqkv + (257 + tid) * EE + k0;   // value weight rows
      float4 a0 = *(const float4*)&wrow[0];
      float4 a1 = *(const float4*)&wrow[4];
      wchunk[0*256 + tid] = a0.x; wchunk[1*256 + tid] = a0.y;
      wchunk[2*256 + tid] = a0.z; wchunk[3*256 + tid] = a0.w;
      wchunk[4*256 + tid] = a1.x; wchunk[5*256 + tid] = a1.y;
      wchunk[6*256 + tid] = a1.z; wchunk[7*256 + tid] = a1.w;
    }
    if (tid < 128) {
      const int c = tid >> 4, f4 = tid & 15;
      *(float4*)&xchunk[c * 64 + f4 * 4] =
          *(const float4*)&x[gbase + (k0 + c) * 4096 + f4 * 4];
    }
    __syncthreads();
    #pragma unroll
    for (int kk = 0; kk < KC; ++kk) {
      const float4 w0 = *(const float4*)&wchunk[kk*256 + i*8];
      const float4 w1 = *(const float4*)&wchunk[kk*256 + i*8 + 4];
      const float4 x0 = *(const float4*)&xchunk[kk*64 + j*8];
      const float4 x1 = *(const float4*)&xchunk[kk*64 + j*8 + 4];
      FMA4(vA0, w0.x, x0) FMA4(vB0, w0.x, x1)
      FMA4(vA1, w0.y, x0) FMA4(vB1, w0.y, x1)
      FMA4(vA2, w0.z, x0) FMA4(vB2, w0.z, x1)
      FMA4(vA3, w0.w, x0) FMA4(vB3, w0.w, x1)
      FMA4(vA4, w1.x, x0) FMA4(vB4, w1.x, x1)
      FMA4(vA5, w1.y, x0) FMA4(vB5, w1.y, x1)
      FMA4(vA6, w1.z, x0) FMA4(vB6, w1.z, x1)
      FMA4(vA7, w1.w, x0) FMA4(vB7, w1.w, x1)
    }
  }

  // ---- Phase 6: relu + gate, pack bf16 into LDS (pure component code) ----
  {
    const float4 cv0 = *(const float4*)&cvs[i*8];
    const float4 cv1 = *(const float4*)&cvs[i*8 + 4];
    #define GATE_ROW(N, CVC)                                            \
    {                                                                   \
      const float bias = bqkv[257 + i*8 + N];                           \
      float4 gA, gB;                                                    \
      gA.x = fmaxf(vA##N.x + bias, 0.f) * (CVC);                        \
      gA.y = fmaxf(vA##N.y + bias, 0.f) * (CVC);                        \
      gA.z = fmaxf(vA##N.z + bias, 0.f) * (CVC);                        \
      gA.w = fmaxf(vA##N.w + bias, 0.f) * (CVC);                        \
      gB.x = fmaxf(vB##N.x + bias, 0.f) * (CVC);                        \
      gB.y = fmaxf(vB##N.y + bias, 0.f) * (CVC);                        \
      gB.z = fmaxf(vB##N.z + bias, 0.f) * (CVC);                        \
      gB.w = fmaxf(vB##N.w + bias, 0.f) * (CVC);                        \
      uint4 U;                                                          \
      U.x = f2bf(gA.x) | (f2bf(gA.y) << 16);                            \
      U.y = f2bf(gA.z) | (f2bf(gA.w) << 16);                            \
      U.z = f2bf(gB.x) | (f2bf(gB.y) << 16);                            \
      U.w = f2bf(gB.z) | (f2bf(gB.w) << 16);                            \
      *(uint4*)&gsu[(i*8 + N) * 32 + j * 4] = U;                        \
    }
    GATE_ROW(0, cv0.x) GATE_ROW(1, cv0.y) GATE_ROW(2, cv0.z) GATE_ROW(3, cv0.w)
    GATE_ROW(4, cv1.x) GATE_ROW(5, cv1.y) GATE_ROW(6, cv1.z) GATE_ROW(7, cv1.w)
    #undef GATE_ROW
  }

  // ---- Phase 7: output GEMM (k over 256 gated channels) ----
  float4 oA0 = z4, oA1 = z4, oA2 = z4, oA3 = z4, oA4 = z4, oA5 = z4, oA6 = z4, oA7 = z4;
  float4 oB0 = z4, oB1 = z4, oB2 = z4, oB3 = z4, oB4 = z4, oB5 = z4, oB6 = z4, oB7 = z4;

  for (int k0 = 0; k0 < HIDN; k0 += KC) {
    __syncthreads();   // publishes gsu on first iter, protects wchunk reuse
    {
      const float* wrow = Wout + tid * HIDN + k0;
      float4 a0 = *(const float4*)&wrow[0];
      float4 a1 = *(const float4*)&wrow[4];
      wchunk[0*256 + tid] = a0.x; wchunk[1*256 + tid] = a0.y;
      wchunk[2*256 + tid] = a0.z; wchunk[3*256 + tid] = a0.w;
      wchunk[4*256 + tid] = a1.x; wchunk[5*256 + tid] = a1.y;
      wchunk[6*256 + tid] = a1.z; wchunk[7*256 + tid] = a1.w;
    }
    __syncthreads();
    #pragma unroll
    for (int kk = 0; kk < KC; ++kk) {
      const float4 w0 = *(const float4*)&wchunk[kk*256 + i*8];
      const float4 w1 = *(const float4*)&wchunk[kk*256 + i*8 + 4];
      const uint4  gu = *(const uint4*)&gsu[(k0 + kk) * 32 + j * 4];
      float4 g0, g1;
      g0.x = bflo(gu.x); g0.y = bfhi(gu.x); g0.z = bflo(gu.y); g0.w = bfhi(gu.y);
      g1.x = bflo(gu.z); g1.y = bfhi(gu.z); g1.z = bflo(gu.w); g1.w = bfhi(gu.w);
      FMA4(oA0, w0.x, g0) FMA4(oB0, w0.x, g1)
      FMA4(oA1, w0.y, g0) FMA4(oB1, w0.y, g1)
      FMA4(oA2, w0.z, g0) FMA4(oB2, w0.z, g1)
      FMA4(oA3, w0.w, g0) FMA4(oB3, w0.w, g1)
      FMA4(oA4, w1.x, g0) FMA4(oB4, w1.x, g1)
      FMA4(oA5, w1.y, g0) FMA4(oB5, w1.y, g1)
      FMA4(oA6, w1.z, g0) FMA4(oB6, w1.z, g1)
      FMA4(oA7, w1.w, g0) FMA4(oB7, w1.w, g1)
    }
  }

  // ---- Phase 8: bias + coalesced store (pure component code) ----
  {
    #define STORE_ROW(N)                                                \
    {                                                                   \
      const int o = i*8 + N;                                            \
      const float bo = bout[o];                                         \
      float* op = out + (b * EE + o) * 4096 + h * 64 + j * 8;           \
      float4 s0, s1;                                                    \
      s0.x = oA##N.x + bo; s0.y = oA##N.y + bo;                         \
      s0.z = oA##N.z + bo; s0.w = oA##N.w + bo;                         \
      s1.x = oB##N.x + bo; s1.y = oB##N.y + bo;                         \
      s1.z = oB##N.z + bo; s1.w = oB##N.w + bo;                         \
      *(float4*)&op[0] = s0;                                            \
      *(float4*)&op[4] = s1;                                            \
    }
    STORE_ROW(0) STORE_ROW(1) STORE_ROW(2) STORE_ROW(3)
    STORE_ROW(4) STORE_ROW(5) STORE_ROW(6) STORE_ROW(7)
    #undef STORE_ROW
  }
}

extern "C" void kernel_launch(void* const* d_in, const int* in_sizes, int n_in,
                              void* d_out, int out_size, void* d_ws, size_t ws_size,
                              hipStream_t stream) {
  const float* x    = (const float*)d_in[0];
  const float* Wqkv = (const float*)d_in[1];
  const float* bqkv = (const float*)d_in[2];
  const float* Wout = (const float*)d_in[3];
  const float* bout = (const float*)d_in[4];
  float* out = (float*)d_out;
  dim3 grid(BB * HH);   // 2048 workgroups, one per (b,h)
  dim3 block(256);
  hipLaunchKernelGGL(sep_attn_fused, grid, block, 0, stream,
                     x, Wqkv, bqkv, Wout, bout, out);
}